// Round 7
// baseline (258.065 us; speedup 1.0000x reference)
//
#include <hip/hip_runtime.h>
#include <hip/hip_bf16.h>

// B=512, K=256, D_MODEL=256, D_INNER=512.
// Identity: Hilbert gather/scatter cancels (per-row model):
// out = slots + LN(SiLU(slots@W1+b1)@W2+b2)*gamma+beta. adj/centroids unused.
//
// R5: 32-row blocks, 4 waves (256 thr), 40KB LDS -> 4 blocks/CU free-running
// (replaces R4's block-wide barrier lockstep across 8 waves; cross-block
// desync overlaps LDS-phase with MFMA/global-phase). Weight prefetch deepened:
// W1 ring-3, W2 ring-4 issued during layer-1 (loads in flight across barrier).

#define MROWS (512*256)
#define DM 256
#define DI 512

typedef __attribute__((ext_vector_type(8))) short  short8;
typedef __attribute__((ext_vector_type(4))) float  f32x4;

static __device__ __forceinline__ unsigned short f2bf(float f) {
    union { float f; unsigned u; } c; c.f = f;
    unsigned r = c.u + 0x7FFFu + ((c.u >> 16) & 1u);   // RNE
    return (unsigned short)(r >> 16);
}
static __device__ __forceinline__ float bf2f(unsigned short h) {
    union { unsigned u; float f; } c; c.u = ((unsigned)h) << 16;
    return c.f;
}
static __device__ __forceinline__ void split2(float x, unsigned short& hi, unsigned short& lo) {
    hi = f2bf(x);
    lo = f2bf(x - bf2f(hi));
}
static __device__ __forceinline__ f32x4 MFMA(short8 a, short8 b, f32x4 c) {
    return __builtin_amdgcn_mfma_f32_16x16x32_bf16(a, b, c, 0, 0, 0);
}

// ---- prep: fragment-major hi/lo weights (layout unchanged since R3).
// W1F frag f = tile16*8+kt (tile16 0..31, kt 0..7), 1024 shorts (512 hi | 512 lo)
//   elem e=lane*8+j  ->  W1[k=kt*32+(lane>>4)*8+j][i=tile16*16+(lane&15)]
// W2F frag f = dtile*16+ks (dtile 0..15, ks 0..15)
//   elem e           ->  W2[i=ks*32+(lane>>4)*8+j][d=dtile*16+(lane&15)]
__global__ void gml_prep(const float* __restrict__ W1, const float* __restrict__ W2,
                         unsigned short* __restrict__ W1F, unsigned short* __restrict__ W2F)
{
    int t = blockIdx.x * 256 + threadIdx.x;      // 0 .. 131071
    int f = t >> 9, e = t & 511;
    int lane = e >> 3, j = e & 7;
    int l15 = lane & 15, lq = lane >> 4;
    {
        int tile16 = f >> 3, kt = f & 7;
        int i = tile16 * 16 + l15;
        int k = kt * 32 + lq * 8 + j;
        unsigned short h, l; split2(W1[k * DI + i], h, l);
        W1F[(size_t)f * 1024 + e]       = h;
        W1F[(size_t)f * 1024 + 512 + e] = l;
    }
    {
        int dtile = f >> 4, ks = f & 15;
        int d = dtile * 16 + l15;
        int i = ks * 32 + lq * 8 + j;
        unsigned short h, l; split2(W2[i * DM + d], h, l);
        W2F[(size_t)f * 1024 + e]       = h;
        W2F[(size_t)f * 1024 + 512 + e] = l;
    }
}

__global__ __launch_bounds__(256, 4)
void gml_main(const float* __restrict__ X,
              const float* __restrict__ b1, const float* __restrict__ b2,
              const float* __restrict__ gamma, const float* __restrict__ beta,
              const unsigned short* __restrict__ W1F, const unsigned short* __restrict__ W2F,
              float* __restrict__ out)
{
    // X hi/lo: [32 rows][256 k] bf16, row stride 512B, byte-swizzle ^((row&7)<<4)
    __shared__ short sXh[32 * 256];   // 16 KB
    __shared__ short sXl[32 * 256];   // 16 KB
    // H chunk hi/lo: [32 rows][64 k] bf16, row stride 128B, same swizzle
    __shared__ short sHh[32 * 64];    // 4 KB
    __shared__ short sHl[32 * 64];    // 4 KB   -> total 40 KB -> 4 blocks/CU
    // LN partials aliased into sXh (dead after the chunk loop)
    float* pS = (float*)sXh;          // [4 strips][32 rows]
    float* pQ = pS + 128;

    const int tid  = threadIdx.x;
    const int w    = tid >> 6;        // wave 0..3 = column strip
    const int lane = tid & 63;
    const int l15  = lane & 15;
    const int lq   = lane >> 4;
    const int rowbase = blockIdx.x * 32;

    // ---- X -> LDS hi/lo. Wave w stages k-slices kt = 2w, 2w+1 for all 32 rows.
    #pragma unroll
    for (int t = 0; t < 2; ++t) {
        const int kt = 2 * w + t;
        #pragma unroll
        for (int rt = 0; rt < 2; ++rt) {
            const int row = rt * 16 + l15;
            const float* xp = X + (size_t)(rowbase + row) * DM + kt * 32 + lq * 8;
            f32x4 xa = *(const f32x4*)xp;
            f32x4 xb = *(const f32x4*)(xp + 4);
            short8 h8, l8;
            #pragma unroll
            for (int j = 0; j < 8; ++j) {
                float v = (j < 4) ? xa[j] : xb[j - 4];
                unsigned short h, l; split2(v, h, l);
                h8[j] = (short)h; l8[j] = (short)l;
            }
            const int byt = (row * 512 + (kt * 32 + lq * 8) * 2) ^ ((row & 7) << 4);
            *(short8*)((char*)sXh + byt) = h8;
            *(short8*)((char*)sXl + byt) = l8;
        }
    }

    f32x4 acc2[2][4];
    #pragma unroll
    for (int rt = 0; rt < 2; ++rt)
        #pragma unroll
        for (int ot = 0; ot < 4; ++ot)
            acc2[rt][ot] = (f32x4){0.f, 0.f, 0.f, 0.f};

    __syncthreads();

    #pragma unroll 1
    for (int c = 0; c < 8; ++c) {
        // ---------- layer 1: wave computes H[0..32][c*64 + w*16 .. +16]
        f32x4 acc1[2] = {(f32x4){0.f,0.f,0.f,0.f}, (f32x4){0.f,0.f,0.f,0.f}};
        const unsigned short* w1p = W1F + (size_t)((c * 4 + w) * 8) * 1024 + lane * 8;
        const unsigned short* w2p = W2F + ((size_t)(w * 4) * 16 + c * 2) * 1024 + lane * 8;

        short8 wb[3][2];                  // W1 ring-3: slot kt%3 holds frag kt
        #pragma unroll
        for (int t = 0; t < 3; ++t) {
            wb[t][0] = *(const short8*)(w1p + t * 1024);
            wb[t][1] = *(const short8*)(w1p + t * 1024 + 512);
        }
        short8 vb[4][2];                  // W2 ring-4, filled during kt=4..7

        #pragma unroll
        for (int kt = 0; kt < 8; ++kt) {
            const int slot = kt % 3;
            short8 ah[2], al[2];
            #pragma unroll
            for (int rt = 0; rt < 2; ++rt) {
                const int row = rt * 16 + l15;
                const int byt = (row * 512 + (kt * 32 + lq * 8) * 2) ^ ((row & 7) << 4);
                ah[rt] = *(const short8*)((char*)sXh + byt);
                al[rt] = *(const short8*)((char*)sXl + byt);
            }
            #pragma unroll
            for (int rt = 0; rt < 2; ++rt) {
                acc1[rt] = MFMA(ah[rt], wb[slot][0], acc1[rt]);
                acc1[rt] = MFMA(ah[rt], wb[slot][1], acc1[rt]);
                acc1[rt] = MFMA(al[rt], wb[slot][0], acc1[rt]);
            }
            if (kt < 5) {                 // prefetch kt+3 into the slot just freed
                wb[slot][0] = *(const short8*)(w1p + (kt + 3) * 1024);
                wb[slot][1] = *(const short8*)(w1p + (kt + 3) * 1024 + 512);
            }
            if (kt >= 4) {                // stage W2 u=kt-4 (u<4 => offset u*16KB)
                const int u = kt - 4;
                vb[u][0] = *(const short8*)(w2p + (size_t)u * 16 * 1024);
                vb[u][1] = *(const short8*)(w2p + (size_t)u * 16 * 1024 + 512);
            }
        }

        // ---------- bias + SiLU + split -> H LDS
        const float bias = b1[c * 64 + w * 16 + l15];
        #pragma unroll
        for (int rt = 0; rt < 2; ++rt) {
            #pragma unroll
            for (int r = 0; r < 4; ++r) {
                const int row = rt * 16 + lq * 4 + r;
                float x = acc1[rt][r] + bias;
                float s = x / (1.f + __expf(-x));
                unsigned short h, l; split2(s, h, l);
                const int byt = (row * 128 + (w * 16 + l15) * 2) ^ ((row & 7) << 4);
                *(short*)((char*)sHh + byt) = (short)h;
                *(short*)((char*)sHl + byt) = (short)l;
            }
        }
        __syncthreads();

        // ---------- layer 2: acc2 += H @ W2[c*64..+64][w*64 .. +64]
        #pragma unroll
        for (int kt2 = 0; kt2 < 2; ++kt2) {
            short8 a2h[2], a2l[2];
            #pragma unroll
            for (int rt = 0; rt < 2; ++rt) {
                const int row = rt * 16 + l15;
                const int byt = (row * 128 + (kt2 * 32 + lq * 8) * 2) ^ ((row & 7) << 4);
                a2h[rt] = *(const short8*)((char*)sHh + byt);
                a2l[rt] = *(const short8*)((char*)sHl + byt);
            }
            #pragma unroll
            for (int ot = 0; ot < 4; ++ot) {
                const int u = kt2 * 4 + ot;
                const int s4 = u & 3;
                #pragma unroll
                for (int rt = 0; rt < 2; ++rt) {
                    acc2[rt][ot] = MFMA(a2h[rt], vb[s4][0], acc2[rt][ot]);
                    acc2[rt][ot] = MFMA(a2h[rt], vb[s4][1], acc2[rt][ot]);
                    acc2[rt][ot] = MFMA(a2l[rt], vb[s4][0], acc2[rt][ot]);
                }
                if (u < 4) {              // prefetch u+4 = (ot, kt2=1) into same slot
                    const size_t off = (size_t)(u * 16 + 1) * 1024;
                    vb[s4][0] = *(const short8*)(w2p + off);
                    vb[s4][1] = *(const short8*)(w2p + off + 512);
                }
            }
        }
        __syncthreads();
    }

    // ---------- epilogue: +b2, block-wide LN over 256 cols, *gamma+beta, +residual
    float b2v[4];
    #pragma unroll
    for (int ot = 0; ot < 4; ++ot) b2v[ot] = b2[w * 64 + ot * 16 + l15];

    #pragma unroll
    for (int rt = 0; rt < 2; ++rt) {
        #pragma unroll
        for (int r = 0; r < 4; ++r) {
            float s = 0.f, q = 0.f;
            #pragma unroll
            for (int ot = 0; ot < 4; ++ot) {
                float v = acc2[rt][ot][r] + b2v[ot];
                acc2[rt][ot][r] = v;
                s += v; q += v * v;
            }
            #pragma unroll
            for (int m = 1; m < 16; m <<= 1) {
                s += __shfl_xor(s, m, 64);
                q += __shfl_xor(q, m, 64);
            }
            if (l15 == 0) {
                const int rowl = rt * 16 + lq * 4 + r;
                pS[w * 32 + rowl] = s;
                pQ[w * 32 + rowl] = q;
            }
        }
    }
    __syncthreads();

    const float inv = 1.f / 256.f;
    #pragma unroll
    for (int rt = 0; rt < 2; ++rt) {
        #pragma unroll
        for (int r = 0; r < 4; ++r) {
            const int rowl = rt * 16 + lq * 4 + r;
            const float s = pS[rowl] + pS[32 + rowl] + pS[64 + rowl] + pS[96 + rowl];
            const float q = pQ[rowl] + pQ[32 + rowl] + pQ[64 + rowl] + pQ[96 + rowl];
            const float mean = s * inv;
            const float rstd = rsqrtf(q * inv - mean * mean + 1e-5f);
            const size_t rb = (size_t)(rowbase + rowl) * DM;
            #pragma unroll
            for (int ot = 0; ot < 4; ++ot) {
                const int col = w * 64 + ot * 16 + l15;
                out[rb + col] = (acc2[rt][ot][r] - mean) * rstd * gamma[col] + beta[col] + X[rb + col];
            }
        }
    }
}

// ---- slow-but-correct fp32 fallback (only if ws is unexpectedly tiny)
__global__ __launch_bounds__(256)
void gml_naive(const float* __restrict__ X, const float* __restrict__ W1,
               const float* __restrict__ b1, const float* __restrict__ W2,
               const float* __restrict__ b2, const float* __restrict__ gamma,
               const float* __restrict__ beta, float* __restrict__ out)
{
    __shared__ float sx[DM];
    __shared__ float sh[DI];
    __shared__ float red[8];
    const int row = blockIdx.x, t = threadIdx.x;
    const float* xr = X + (size_t)row * DM;
    sx[t] = xr[t];
    __syncthreads();
    #pragma unroll
    for (int rep = 0; rep < 2; ++rep) {
        int i = t + rep * 256;
        float a = 0.f;
        for (int k = 0; k < DM; ++k) a += sx[k] * W1[k * DI + i];
        a += b1[i];
        sh[i] = a / (1.f + __expf(-a));
    }
    __syncthreads();
    float y = 0.f;
    for (int i = 0; i < DI; ++i) y += sh[i] * W2[i * DM + t];
    y += b2[t];
    float s = y, q = y * y;
    for (int m = 1; m < 64; m <<= 1) { s += __shfl_xor(s, m, 64); q += __shfl_xor(q, m, 64); }
    if ((t & 63) == 0) { red[t >> 6] = s; red[4 + (t >> 6)] = q; }
    __syncthreads();
    const float sum = red[0] + red[1] + red[2] + red[3];
    const float ssq = red[4] + red[5] + red[6] + red[7];
    const float mean = sum / 256.f;
    const float rstd = rsqrtf(ssq / 256.f - mean * mean + 1e-5f);
    out[(size_t)row * DM + t] = (y - mean) * rstd * gamma[t] + beta[t] + xr[t];
}

extern "C" void kernel_launch(void* const* d_in, const int* in_sizes, int n_in,
                              void* d_out, int out_size, void* d_ws, size_t ws_size,
                              hipStream_t stream)
{
    const float* slots = (const float*)d_in[0];
    // d_in[1]=adj, d_in[2]=centroids : unused (permutation cancels)
    const float* W1    = (const float*)d_in[3];
    const float* b1    = (const float*)d_in[4];
    const float* W2    = (const float*)d_in[5];
    const float* b2    = (const float*)d_in[6];
    const float* gamma = (const float*)d_in[7];
    const float* beta  = (const float*)d_in[8];
    float* out = (float*)d_out;

    const size_t need = (size_t)2 * 256 * 1024 * sizeof(unsigned short);  // 1 MiB
    if (ws_size >= need) {
        unsigned short* W1F = (unsigned short*)d_ws;
        unsigned short* W2F = W1F + (size_t)256 * 1024;
        hipLaunchKernelGGL(gml_prep, dim3(512), dim3(256), 0, stream, W1, W2, W1F, W2F);
        hipLaunchKernelGGL(gml_main, dim3(MROWS / 32), dim3(256), 0, stream,
                           slots, b1, b2, gamma, beta, W1F, W2F, out);
    } else {
        hipLaunchKernelGGL(gml_naive, dim3(MROWS), dim3(256), 0, stream,
                           slots, W1, b1, W2, b2, gamma, beta, out);
    }
}

// Round 8
// 210.055 us; speedup vs baseline: 1.2286x; 1.2286x over previous
//
#include <hip/hip_runtime.h>
#include <hip/hip_bf16.h>

// B=512, K=256, D_MODEL=256, D_INNER=512.
// Identity: Hilbert gather/scatter cancels (per-row model):
// out = slots + LN(SiLU(slots@W1+b1)@W2+b2)*gamma+beta. adj/centroids unused.
//
// R6 = R4 structure + 2-pass numerics + full-chunk weight prefetch.
//  - weights kept HI-ONLY (drop X*W1l / H*W2l terms, ~2^-10 relative error):
//    halves weight stream (4.3 -> 2.1 GB) and cuts MFMA work by 1/3.
//  - W2 chunk frags vb[8] issued during layer-1 (in flight across barrier);
//    W1 4-slot ring prefetches next chunk during kt>=4. Static indices only.
//  - 64-row blocks, 8 waves (512 thr), X hi/lo + H hi/lo in LDS = 80 KB,
//    2 blocks/CU, launch_bounds(512,4).

#define MROWS (512*256)
#define DM 256
#define DI 512

typedef __attribute__((ext_vector_type(8))) short  short8;
typedef __attribute__((ext_vector_type(4))) float  f32x4;

static __device__ __forceinline__ unsigned short f2bf(float f) {
    union { float f; unsigned u; } c; c.f = f;
    unsigned r = c.u + 0x7FFFu + ((c.u >> 16) & 1u);   // RNE
    return (unsigned short)(r >> 16);
}
static __device__ __forceinline__ float bf2f(unsigned short h) {
    union { unsigned u; float f; } c; c.u = ((unsigned)h) << 16;
    return c.f;
}
static __device__ __forceinline__ void split2(float x, unsigned short& hi, unsigned short& lo) {
    hi = f2bf(x);
    lo = f2bf(x - bf2f(hi));
}
static __device__ __forceinline__ f32x4 MFMA(short8 a, short8 b, f32x4 c) {
    return __builtin_amdgcn_mfma_f32_16x16x32_bf16(a, b, c, 0, 0, 0);
}

// ---- prep: fragment-major HI-only bf16 weights (512 shorts = 1KB per frag).
// W1H frag f = tile16*8+kt (tile16 0..31, kt 0..7):
//   elem e=lane*8+j -> W1[k=kt*32+(lane>>4)*8+j][i=tile16*16+(lane&15)]
// W2H frag f = dtile*16+ks (dtile 0..15, ks 0..15):
//   elem e          -> W2[i=ks*32+(lane>>4)*8+j][d=dtile*16+(lane&15)]
__global__ void gml_prep(const float* __restrict__ W1, const float* __restrict__ W2,
                         unsigned short* __restrict__ W1H, unsigned short* __restrict__ W2H)
{
    int t = blockIdx.x * 256 + threadIdx.x;      // 0 .. 131071
    int f = t >> 9, e = t & 511;
    int lane = e >> 3, j = e & 7;
    int l15 = lane & 15, lq = lane >> 4;
    {
        int tile16 = f >> 3, kt = f & 7;
        int i = tile16 * 16 + l15;
        int k = kt * 32 + lq * 8 + j;
        W1H[(size_t)f * 512 + e] = f2bf(W1[k * DI + i]);
    }
    {
        int dtile = f >> 4, ks = f & 15;
        int d = dtile * 16 + l15;
        int i = ks * 32 + lq * 8 + j;
        W2H[(size_t)f * 512 + e] = f2bf(W2[i * DM + d]);
    }
}

__global__ __launch_bounds__(512, 4)
void gml_main(const float* __restrict__ X,
              const float* __restrict__ b1, const float* __restrict__ b2,
              const float* __restrict__ gamma, const float* __restrict__ beta,
              const unsigned short* __restrict__ W1H, const unsigned short* __restrict__ W2H,
              float* __restrict__ out)
{
    // X hi/lo: [64 rows][256 k] bf16, row stride 512B, byte-swizzle ^((row&7)<<4)
    __shared__ short sXh[64 * 256];   // 32 KB
    __shared__ short sXl[64 * 256];   // 32 KB
    // H chunk hi/lo: [64 rows][64 k] bf16, row stride 128B, same swizzle
    __shared__ short sHh[64 * 64];    // 8 KB
    __shared__ short sHl[64 * 64];    // 8 KB   -> total exactly 80 KB
    // LN partials aliased into sXl (dead after the chunk loop)
    float* pS = (float*)sXl;          // [4 strips][64 rows]
    float* pQ = pS + 256;

    const int tid  = threadIdx.x;
    const int w    = tid >> 6;        // wave 0..7
    const int lane = tid & 63;
    const int l15  = lane & 15;
    const int lq   = lane >> 4;
    const int half = w >> 2;          // row half owned for compute
    const int cs   = w & 3;           // column strip
    const int rowbase = blockIdx.x * 64;

    // ---- X -> LDS hi/lo. Wave w loads k-slice [w*32, w*32+32) for all 64 rows.
    #pragma unroll
    for (int rt = 0; rt < 4; ++rt) {
        const int row = rt * 16 + l15;
        const float* xp = X + (size_t)(rowbase + row) * DM + w * 32 + lq * 8;
        f32x4 xa = *(const f32x4*)xp;
        f32x4 xb = *(const f32x4*)(xp + 4);
        short8 h8, l8;
        #pragma unroll
        for (int j = 0; j < 8; ++j) {
            float v = (j < 4) ? xa[j] : xb[j - 4];
            unsigned short h, l; split2(v, h, l);
            h8[j] = (short)h; l8[j] = (short)l;
        }
        const int byt = (row * 512 + (w * 32 + lq * 8) * 2) ^ ((row & 7) << 4);
        *(short8*)((char*)sXh + byt) = h8;
        *(short8*)((char*)sXl + byt) = l8;
    }

    f32x4 acc2[2][4];
    #pragma unroll
    for (int rt = 0; rt < 2; ++rt)
        #pragma unroll
        for (int ot = 0; ot < 4; ++ot)
            acc2[rt][ot] = (f32x4){0.f, 0.f, 0.f, 0.f};

    // ---- W1 ring prologue: chunk-0 frags kt=0..3 (global, overlaps barrier)
    short8 w1r[4];
    #pragma unroll
    for (int t = 0; t < 4; ++t)
        w1r[t] = *(const short8*)(W1H + (size_t)(cs * 8 + t) * 512 + lane * 8);

    __syncthreads();

    #pragma unroll 1
    for (int c = 0; c < 8; ++c) {
        const size_t fb1  = (size_t)((c * 4 + cs) * 8);          // this chunk's W1 frag base
        const size_t fb1n = (size_t)(((c + 1) * 4 + cs) * 8);    // next chunk's

        // ---------- layer 1: wave computes H[half*32..+32][c*64 + cs*16 .. +16]
        f32x4 acc1[2] = {(f32x4){0.f,0.f,0.f,0.f}, (f32x4){0.f,0.f,0.f,0.f}};
        short8 vb[8];                                // W2 chunk frags, filled below

        #pragma unroll
        for (int kt = 0; kt < 8; ++kt) {
            const int slot = kt & 3;
            // issue W2 frag u=kt for this chunk (used after the barrier)
            {
                const size_t f2 = (size_t)((cs * 4 + (kt & 3)) * 16 + c * 2 + (kt >> 2));
                vb[kt] = *(const short8*)(W2H + f2 * 512 + lane * 8);
            }
            short8 ah[2], al[2];
            #pragma unroll
            for (int rt = 0; rt < 2; ++rt) {
                const int row = half * 32 + rt * 16 + l15;
                const int byt = (row * 512 + (kt * 32 + lq * 8) * 2) ^ ((row & 7) << 4);
                ah[rt] = *(const short8*)((char*)sXh + byt);
                al[rt] = *(const short8*)((char*)sXl + byt);
            }
            #pragma unroll
            for (int rt = 0; rt < 2; ++rt) {
                acc1[rt] = MFMA(ah[rt], w1r[slot], acc1[rt]);
                acc1[rt] = MFMA(al[rt], w1r[slot], acc1[rt]);
            }
            // refill the slot just consumed
            if (kt < 4) {
                w1r[slot] = *(const short8*)(W1H + (fb1 + kt + 4) * 512 + lane * 8);
            } else if (c < 7) {
                w1r[slot] = *(const short8*)(W1H + (fb1n + kt - 4) * 512 + lane * 8);
            }
        }

        // ---------- bias + SiLU + split -> H LDS
        const float bias = b1[c * 64 + cs * 16 + l15];
        #pragma unroll
        for (int rt = 0; rt < 2; ++rt) {
            #pragma unroll
            for (int r = 0; r < 4; ++r) {
                const int row = half * 32 + rt * 16 + lq * 4 + r;
                float x = acc1[rt][r] + bias;
                float s = x / (1.f + __expf(-x));
                unsigned short h, l; split2(s, h, l);
                const int byt = (row * 128 + (cs * 16 + l15) * 2) ^ ((row & 7) << 4);
                *(short*)((char*)sHh + byt) = (short)h;
                *(short*)((char*)sHl + byt) = (short)l;
            }
        }
        __syncthreads();

        // ---------- layer 2: acc2 += H @ W2h[c*64..+64][cs*64 .. +64]
        #pragma unroll
        for (int kt2 = 0; kt2 < 2; ++kt2) {
            short8 a2h[2], a2l[2];
            #pragma unroll
            for (int rt = 0; rt < 2; ++rt) {
                const int row = half * 32 + rt * 16 + l15;
                const int byt = (row * 128 + (kt2 * 32 + lq * 8) * 2) ^ ((row & 7) << 4);
                a2h[rt] = *(const short8*)((char*)sHh + byt);
                a2l[rt] = *(const short8*)((char*)sHl + byt);
            }
            #pragma unroll
            for (int ot = 0; ot < 4; ++ot) {
                const int u = kt2 * 4 + ot;
                #pragma unroll
                for (int rt = 0; rt < 2; ++rt) {
                    acc2[rt][ot] = MFMA(a2h[rt], vb[u], acc2[rt][ot]);
                    acc2[rt][ot] = MFMA(a2l[rt], vb[u], acc2[rt][ot]);
                }
            }
        }
        __syncthreads();
    }

    // ---------- epilogue: +b2, block-wide LN over 256 cols, *gamma+beta, +residual
    float b2v[4];
    #pragma unroll
    for (int ot = 0; ot < 4; ++ot) b2v[ot] = b2[cs * 64 + ot * 16 + l15];

    #pragma unroll
    for (int rt = 0; rt < 2; ++rt) {
        #pragma unroll
        for (int r = 0; r < 4; ++r) {
            float s = 0.f, q = 0.f;
            #pragma unroll
            for (int ot = 0; ot < 4; ++ot) {
                float v = acc2[rt][ot][r] + b2v[ot];
                acc2[rt][ot][r] = v;
                s += v; q += v * v;
            }
            #pragma unroll
            for (int m = 1; m < 16; m <<= 1) {
                s += __shfl_xor(s, m, 64);
                q += __shfl_xor(q, m, 64);
            }
            if (l15 == 0) {
                const int rowl = half * 32 + rt * 16 + lq * 4 + r;
                pS[cs * 64 + rowl] = s;
                pQ[cs * 64 + rowl] = q;
            }
        }
    }
    __syncthreads();

    const float inv = 1.f / 256.f;
    #pragma unroll
    for (int rt = 0; rt < 2; ++rt) {
        #pragma unroll
        for (int r = 0; r < 4; ++r) {
            const int rowl = half * 32 + rt * 16 + lq * 4 + r;
            const float s = pS[rowl] + pS[64 + rowl] + pS[128 + rowl] + pS[192 + rowl];
            const float q = pQ[rowl] + pQ[64 + rowl] + pQ[128 + rowl] + pQ[192 + rowl];
            const float mean = s * inv;
            const float rstd = rsqrtf(q * inv - mean * mean + 1e-5f);
            const size_t rb = (size_t)(rowbase + rowl) * DM;
            #pragma unroll
            for (int ot = 0; ot < 4; ++ot) {
                const int col = cs * 64 + ot * 16 + l15;
                out[rb + col] = (acc2[rt][ot][r] - mean) * rstd * gamma[col] + beta[col] + X[rb + col];
            }
        }
    }
}

// ---- slow-but-correct fp32 fallback (only if ws is unexpectedly tiny)
__global__ __launch_bounds__(256)
void gml_naive(const float* __restrict__ X, const float* __restrict__ W1,
               const float* __restrict__ b1, const float* __restrict__ W2,
               const float* __restrict__ b2, const float* __restrict__ gamma,
               const float* __restrict__ beta, float* __restrict__ out)
{
    __shared__ float sx[DM];
    __shared__ float sh[DI];
    __shared__ float red[8];
    const int row = blockIdx.x, t = threadIdx.x;
    const float* xr = X + (size_t)row * DM;
    sx[t] = xr[t];
    __syncthreads();
    #pragma unroll
    for (int rep = 0; rep < 2; ++rep) {
        int i = t + rep * 256;
        float a = 0.f;
        for (int k = 0; k < DM; ++k) a += sx[k] * W1[k * DI + i];
        a += b1[i];
        sh[i] = a / (1.f + __expf(-a));
    }
    __syncthreads();
    float y = 0.f;
    for (int i = 0; i < DI; ++i) y += sh[i] * W2[i * DM + t];
    y += b2[t];
    float s = y, q = y * y;
    for (int m = 1; m < 64; m <<= 1) { s += __shfl_xor(s, m, 64); q += __shfl_xor(q, m, 64); }
    if ((t & 63) == 0) { red[t >> 6] = s; red[4 + (t >> 6)] = q; }
    __syncthreads();
    const float sum = red[0] + red[1] + red[2] + red[3];
    const float ssq = red[4] + red[5] + red[6] + red[7];
    const float mean = sum / 256.f;
    const float rstd = rsqrtf(ssq / 256.f - mean * mean + 1e-5f);
    out[(size_t)row * DM + t] = (y - mean) * rstd * gamma[t] + beta[t] + xr[t];
}

extern "C" void kernel_launch(void* const* d_in, const int* in_sizes, int n_in,
                              void* d_out, int out_size, void* d_ws, size_t ws_size,
                              hipStream_t stream)
{
    const float* slots = (const float*)d_in[0];
    // d_in[1]=adj, d_in[2]=centroids : unused (permutation cancels)
    const float* W1    = (const float*)d_in[3];
    const float* b1    = (const float*)d_in[4];
    const float* W2    = (const float*)d_in[5];
    const float* b2    = (const float*)d_in[6];
    const float* gamma = (const float*)d_in[7];
    const float* beta  = (const float*)d_in[8];
    float* out = (float*)d_out;

    const size_t need = (size_t)2 * 256 * 512 * sizeof(unsigned short);  // 512 KiB
    if (ws_size >= need) {
        unsigned short* W1H = (unsigned short*)d_ws;
        unsigned short* W2H = W1H + (size_t)256 * 512;
        hipLaunchKernelGGL(gml_prep, dim3(512), dim3(256), 0, stream, W1, W2, W1H, W2H);
        hipLaunchKernelGGL(gml_main, dim3(MROWS / 64), dim3(512), 0, stream,
                           slots, b1, b2, gamma, beta, W1H, W2H, out);
    } else {
        hipLaunchKernelGGL(gml_naive, dim3(MROWS), dim3(256), 0, stream,
                           slots, W1, b1, W2, b2, gamma, beta, out);
    }
}